// Round 2
// baseline (99.299 us; speedup 1.0000x reference)
//
#include <hip/hip_runtime.h>
#include <hip/hip_bf16.h>

// ArgumentLocalLogits: BS=16, CTX_PER=1024, ARGS_PER=32, KEY_DIM=128, D_MODEL=512
// rows[p] = p>>10 ; logits[p] = dot(Q[p>>10], keys[(p>>15)*1024 + (p&1023)])
// Restructure: logits = (Q @ W^T) @ ctx^T + Q.b
// ws: Qp bf16 [512][512] + qb f32 [512]
// out: [P floats rows-as-float][P floats logits]
//
// R8: (a) packed f32->bf16 via __float22bfloat162_rn (v_cvt_pk_bf16_f32, ~4x
// fewer VALU ops than the old bit-twiddle RNE); (b) main = zero-LDS,
// zero-barrier streaming: 1024 blocks x 2 waves, each wave owns a full-K
// 16x16 tile. A-frags come straight from Qp global (32 KB/state, L1-hot;
// both waves + sibling blocks share). Both waves of a block read the SAME
// 16 ctx rows (L1 dedup) -> ctx HBM stays 33.5 MB. 4 blocks/CU, deep unroll.

#define BSZ        16
#define CTX_PER    1024
#define ARGS_PER   32
#define KD         128
#define DM         512
#define N_ARGS     (BSZ * ARGS_PER)    // 512
#define P_TOTAL    (N_ARGS * CTX_PER)  // 524288

typedef __attribute__((ext_vector_type(8))) short short8;
typedef __attribute__((ext_vector_type(4))) float float4v;

__device__ inline short bf16_of(float x) {
    unsigned u = __builtin_bit_cast(unsigned, x);
    unsigned r = (u + 0x7fffu + ((u >> 16) & 1u)) >> 16;   // RNE
    return (short)r;
}

// packed RNE conversion: compiler lowers __float22bfloat162_rn to
// v_cvt_pk_bf16_f32 (2 elts/instr) instead of ~4 VALU ops per element.
__device__ inline short8 cvt8(float4 lo, float4 hi) {
    union { short8 s; __hip_bfloat162 h[4]; } u;
    u.h[0] = __float22bfloat162_rn(make_float2(lo.x, lo.y));
    u.h[1] = __float22bfloat162_rn(make_float2(lo.z, lo.w));
    u.h[2] = __float22bfloat162_rn(make_float2(hi.x, hi.y));
    u.h[3] = __float22bfloat162_rn(make_float2(hi.z, hi.w));
    return u.s;
}

// Qp[a][m] = sum_d arg[a][d] * W[m][d]  (bf16), qb[a] = dot(arg[a], b)
// grid 256: mtile = b>>3 (16 args), ntile = (b&7)*4 + wave (16 W-rows). 1 MFMA tile per wave.
__global__ __launch_bounds__(256) void qproj_kernel(
    const float* __restrict__ arg, const float* __restrict__ W,
    const float* __restrict__ b, short* __restrict__ Qp, float* __restrict__ qb)
{
    const int t = threadIdx.x, lane = t & 63, wave = t >> 6;
    const int mtile = blockIdx.x >> 3;
    const int ntile = (blockIdx.x & 7) * 4 + wave;
    const int n = lane & 15, quad = lane >> 4;

    // A[m=arg][k=d]: m = lane&15, k = quad*8+j
    const float* asrc = arg + (size_t)(mtile * 16 + n) * KD + quad * 8;
    short8 afr[4];
    #pragma unroll
    for (int kt = 0; kt < 4; ++kt)
        afr[kt] = cvt8(*(const float4*)(asrc + kt * 32), *(const float4*)(asrc + kt * 32 + 4));

    // B[k=d][n=W-row]: n = lane&15
    const float* wsrc = W + (size_t)(ntile * 16 + n) * KD + quad * 8;
    float4v acc = {0.f, 0.f, 0.f, 0.f};
    #pragma unroll
    for (int kt = 0; kt < 4; ++kt) {
        short8 bfr = cvt8(*(const float4*)(wsrc + kt * 32), *(const float4*)(wsrc + kt * 32 + 4));
        acc = __builtin_amdgcn_mfma_f32_16x16x32_bf16(afr[kt], bfr, acc, 0, 0, 0);
    }
    // D: col = lane&15 (= W row-in-tile), row = quad*4+r (= arg-in-tile)
    #pragma unroll
    for (int r = 0; r < 4; ++r)
        Qp[(size_t)(mtile * 16 + quad * 4 + r) * DM + ntile * 16 + n] = bf16_of(acc[r]);

    // qb: only one n-group per m-tile computes it
    if ((blockIdx.x & 7) == 0) {
        __shared__ float red[16][17];
        const int al = t >> 4, seg = t & 15;
        const float* qrow = arg + (size_t)(mtile * 16 + al) * KD + seg * 8;
        float p = 0.f;
        #pragma unroll
        for (int j = 0; j < 8; ++j) p += qrow[j] * b[seg * 8 + j];
        red[al][seg] = p;
        __syncthreads();
        if (t < 16) {
            float ssum = 0.f;
            #pragma unroll
            for (int j = 0; j < 16; ++j) ssum += red[t][j];
            qb[mtile * 16 + t] = ssum;
        }
    }
}

// grid 1024 = 16 states x 64 chunks of 16 ctx rows. Block = 2 waves (128 thr).
// Wave w = arg half (w*16..+16) x the block's 16 ctx rows, full K=512.
// No LDS, no barriers. A-frags from Qp global (L1-hot, 32 KB/state);
// ctx global->reg->cvt_pk->MFMA. Both waves read the same ctx rows (L1 dedup).
__global__ void main_kernel(
    const float* __restrict__ ctx, const short* __restrict__ Qp,
    const float* __restrict__ qb, float* __restrict__ out)
{
    const int t = threadIdx.x, lane = t & 63, wave = t >> 6;
    const int s = blockIdx.x >> 6;
    const int chunk = blockIdx.x & 63;

    const int n = lane & 15, quad = lane >> 4;
    const int A16 = wave * 16;                        // arg half

    // rows output (constant per arg-row) — fully independent, issue first
    {
        const int a = t >> 2, c4 = (t & 3) * 4;       // 32 args x 16 cols / 128 thr
        const int ga = s * ARGS_PER + a;
        const float gaf = (float)ga;
        *(float4*)(out + (size_t)ga * CTX_PER + chunk * 16 + c4) =
            make_float4(gaf, gaf, gaf, gaf);
    }

    // ctx source: row chunk*16 + n, dim segment quad*8 + kt*32
    const float* csrc = ctx + (size_t)(s * CTX_PER + chunk * 16 + n) * DM + quad * 8;
    // A source: Qp row s*32 + A16 + n, same dim segment
    const short* qsrc = Qp + (size_t)(s * 32 + A16 + n) * DM + quad * 8;

    float4v acc = {0.f, 0.f, 0.f, 0.f};
    #pragma unroll
    for (int kt = 0; kt < 16; ++kt) {
        const float4 lo = *(const float4*)(csrc + kt * 32);
        const float4 hi = *(const float4*)(csrc + kt * 32 + 4);
        short8 bfr = cvt8(lo, hi);                     // B[k][n=ctx row]
        short8 a   = *(const short8*)(qsrc + kt * 32); // A[m=arg][k]
        acc = __builtin_amdgcn_mfma_f32_16x16x32_bf16(a, bfr, acc, 0, 0, 0);
    }

    // D: col = lane&15 = ctx row-in-tile (n), row = quad*4+r = arg-in-tile
    const int ga0 = s * ARGS_PER + A16 + quad * 4;
    const float4 qv = *(const float4*)(qb + ga0);      // 16B-aligned
    float* obase = out + P_TOTAL + (size_t)ga0 * CTX_PER + chunk * 16 + n;
    obase[0]           = acc[0] + qv.x;
    obase[CTX_PER]     = acc[1] + qv.y;
    obase[2 * CTX_PER] = acc[2] + qv.z;
    obase[3 * CTX_PER] = acc[3] + qv.w;
}

extern "C" void kernel_launch(void* const* d_in, const int* in_sizes, int n_in,
                              void* d_out, int out_size, void* d_ws, size_t ws_size,
                              hipStream_t stream)
{
    // setup_inputs order: bs, arg_ids, ctx_ids, arg_values, ctx_values, W, b
    const float* arg_values = (const float*)d_in[3];
    const float* ctx_values = (const float*)d_in[4];
    const float* W          = (const float*)d_in[5];
    const float* b          = (const float*)d_in[6];
    float* out = (float*)d_out;

    short* Qp = (short*)d_ws;
    float* qb = (float*)((char*)d_ws + (size_t)N_ARGS * DM * sizeof(short));

    qproj_kernel<<<256, 256, 0, stream>>>(arg_values, W, b, Qp, qb);
    main_kernel<<<BSZ * 64, 128, 0, stream>>>(ctx_values, Qp, qb, out);
}

// Round 3
// 95.133 us; speedup vs baseline: 1.0438x; 1.0438x over previous
//
#include <hip/hip_runtime.h>
#include <hip/hip_bf16.h>

// ArgumentLocalLogits: BS=16, CTX_PER=1024, ARGS_PER=32, KEY_DIM=128, D_MODEL=512
// rows[p] = p>>10 ; logits[p] = dot(Q[p>>10], keys[(p>>15)*1024 + (p&1023)])
// Restructure: logits = (Q @ W^T) @ ctx^T + Q.b
// ws: Qp bf16 [512][512] + qb f32 [512]
// out: [P floats rows-as-float][P floats logits]
//
// R9: R6's winning shape (4-wave K-split, 256 thr, Sp cross-wave reduce) minus
// the staging that had ZERO reuse (K-split means each Qp/ctx byte was read
// from LDS exactly once). All 16 VMEM loads per wave issued up front
// (MLP ~16 KB/wave): 8 short8 A-frags from L2-hot Qp + 8 float4-pair ctx
// from HBM (16 rows x 128 B contiguous = full lines). Packed
// v_cvt_pk_bf16_f32. LDS = 8 KB Sp only -> launch_bounds(256,4),
// grid 1024 = exactly 4 blocks/CU single-gen (R6 had a 1-block/CU tail gen).
// ONE barrier (R6 had 3).

#define BSZ        16
#define CTX_PER    1024
#define ARGS_PER   32
#define KD         128
#define DM         512
#define N_ARGS     (BSZ * ARGS_PER)    // 512
#define P_TOTAL    (N_ARGS * CTX_PER)  // 524288

typedef __attribute__((ext_vector_type(8))) short short8;
typedef __attribute__((ext_vector_type(4))) float float4v;

__device__ inline short bf16_of(float x) {
    unsigned u = __builtin_bit_cast(unsigned, x);
    unsigned r = (u + 0x7fffu + ((u >> 16) & 1u)) >> 16;   // RNE
    return (short)r;
}

// packed RNE conversion: lowers to v_cvt_pk_bf16_f32 (2 elts/instr)
__device__ inline short8 cvt8(float4 lo, float4 hi) {
    union { short8 s; __hip_bfloat162 h[4]; } u;
    u.h[0] = __float22bfloat162_rn(make_float2(lo.x, lo.y));
    u.h[1] = __float22bfloat162_rn(make_float2(lo.z, lo.w));
    u.h[2] = __float22bfloat162_rn(make_float2(hi.x, hi.y));
    u.h[3] = __float22bfloat162_rn(make_float2(hi.z, hi.w));
    return u.s;
}

// Qp[a][m] = sum_d arg[a][d] * W[m][d]  (bf16), qb[a] = dot(arg[a], b)
// grid 256: mtile = b>>3 (16 args), ntile = (b&7)*4 + wave (16 W-rows).
__global__ __launch_bounds__(256) void qproj_kernel(
    const float* __restrict__ arg, const float* __restrict__ W,
    const float* __restrict__ b, short* __restrict__ Qp, float* __restrict__ qb)
{
    const int t = threadIdx.x, lane = t & 63, wave = t >> 6;
    const int mtile = blockIdx.x >> 3;
    const int ntile = (blockIdx.x & 7) * 4 + wave;
    const int n = lane & 15, quad = lane >> 4;

    // A[m=arg][k=d]: m = lane&15, k = quad*8+j
    const float* asrc = arg + (size_t)(mtile * 16 + n) * KD + quad * 8;
    short8 afr[4];
    #pragma unroll
    for (int kt = 0; kt < 4; ++kt)
        afr[kt] = cvt8(*(const float4*)(asrc + kt * 32), *(const float4*)(asrc + kt * 32 + 4));

    // B[k=d][n=W-row]: n = lane&15
    const float* wsrc = W + (size_t)(ntile * 16 + n) * KD + quad * 8;
    float4v acc = {0.f, 0.f, 0.f, 0.f};
    #pragma unroll
    for (int kt = 0; kt < 4; ++kt) {
        short8 bfr = cvt8(*(const float4*)(wsrc + kt * 32), *(const float4*)(wsrc + kt * 32 + 4));
        acc = __builtin_amdgcn_mfma_f32_16x16x32_bf16(afr[kt], bfr, acc, 0, 0, 0);
    }
    // D: col = lane&15 (= W row-in-tile), row = quad*4+r (= arg-in-tile)
    #pragma unroll
    for (int r = 0; r < 4; ++r)
        Qp[(size_t)(mtile * 16 + quad * 4 + r) * DM + ntile * 16 + n] = bf16_of(acc[r]);

    // qb: only one n-group per m-tile computes it
    if ((blockIdx.x & 7) == 0) {
        __shared__ float red[16][17];
        const int al = t >> 4, seg = t & 15;
        const float* qrow = arg + (size_t)(mtile * 16 + al) * KD + seg * 8;
        float p = 0.f;
        #pragma unroll
        for (int j = 0; j < 8; ++j) p += qrow[j] * b[seg * 8 + j];
        red[al][seg] = p;
        __syncthreads();
        if (t < 16) {
            float ssum = 0.f;
            #pragma unroll
            for (int j = 0; j < 16; ++j) ssum += red[t][j];
            qb[mtile * 16 + t] = ssum;
        }
    }
}

// grid 1024 = 16 states x 64 chunks of 16 ctx rows. Block = 4 waves (256 thr).
// Wave w owns K-slice [w*128, w*128+128) for BOTH 16-arg halves x 16 ctx rows:
// 2 independent 4-MFMA chains. All loads direct global->reg (no staging LDS:
// K-split means zero cross-wave byte reuse). LDS = 8 KB Sp reduce only.
__global__ __launch_bounds__(256, 4) void main_kernel(
    const float* __restrict__ ctx, const short* __restrict__ Qp,
    const float* __restrict__ qb, float* __restrict__ out)
{
    __shared__ float Sp[4 * 512];                     // [wave][32 args][16 cols]

    const int t = threadIdx.x, lane = t & 63, wave = t >> 6;
    const int s = blockIdx.x >> 6;
    const int chunk = blockIdx.x & 63;

    const int n = lane & 15, quad = lane >> 4;
    const int k0 = wave * 128;                        // this wave's K-slice

    // ctx loads (HBM): row chunk*16+n, cols k0 + kt*32 + quad*8 .. +8
    // wave footprint per kt: 16 rows x 128 B contiguous = full cache lines
    const float* csrc = ctx + (size_t)(s * CTX_PER + chunk * 16 + n) * DM + k0 + quad * 8;
    float4 clo[4], chi[4];
    #pragma unroll
    for (int kt = 0; kt < 4; ++kt) {
        clo[kt] = *(const float4*)(csrc + kt * 32);
        chi[kt] = *(const float4*)(csrc + kt * 32 + 4);
    }

    // A-frag loads (L2-hot Qp, 32 KB/state): rows s*32+n and +16, same cols
    const short* qsrc = Qp + (size_t)(s * 32 + n) * DM + k0 + quad * 8;
    short8 a0[4], a1[4];
    #pragma unroll
    for (int kt = 0; kt < 4; ++kt) {
        a0[kt] = *(const short8*)(qsrc + kt * 32);
        a1[kt] = *(const short8*)(qsrc + 16 * DM + kt * 32);
    }

    float4v acc0 = {0.f, 0.f, 0.f, 0.f};
    float4v acc1 = {0.f, 0.f, 0.f, 0.f};
    #pragma unroll
    for (int kt = 0; kt < 4; ++kt) {
        short8 bfr = cvt8(clo[kt], chi[kt]);           // B[k][n=ctx row]
        acc0 = __builtin_amdgcn_mfma_f32_16x16x32_bf16(a0[kt], bfr, acc0, 0, 0, 0);
        acc1 = __builtin_amdgcn_mfma_f32_16x16x32_bf16(a1[kt], bfr, acc1, 0, 0, 0);
    }

    // D: col = lane&15 = ctx row-in-tile (n), row = quad*4+r = arg-in-tile
    #pragma unroll
    for (int r = 0; r < 4; ++r) {
        Sp[wave * 512 + (quad * 4 + r) * 16 + n]      = acc0[r];
        Sp[wave * 512 + (16 + quad * 4 + r) * 16 + n] = acc1[r];
    }
    __syncthreads();

    // reduce 4 wave-partials + qb, write logits + rows (float2)
    const int a = t >> 3, c2 = (t & 7) * 2;
    const int base = a * 16 + c2;
    float v0 = Sp[base]     + Sp[512 + base]     + Sp[1024 + base]     + Sp[1536 + base];
    float v1 = Sp[base + 1] + Sp[512 + base + 1] + Sp[1024 + base + 1] + Sp[1536 + base + 1];
    const int ga = s * ARGS_PER + a;
    const float qbv = qb[ga];
    const size_t off = (size_t)ga * CTX_PER + chunk * 16 + c2;
    *(float2*)(out + P_TOTAL + off) = make_float2(v0 + qbv, v1 + qbv);
    *(float2*)(out + off)           = make_float2((float)ga, (float)ga);
}

extern "C" void kernel_launch(void* const* d_in, const int* in_sizes, int n_in,
                              void* d_out, int out_size, void* d_ws, size_t ws_size,
                              hipStream_t stream)
{
    // setup_inputs order: bs, arg_ids, ctx_ids, arg_values, ctx_values, W, b
    const float* arg_values = (const float*)d_in[3];
    const float* ctx_values = (const float*)d_in[4];
    const float* W          = (const float*)d_in[5];
    const float* b          = (const float*)d_in[6];
    float* out = (float*)d_out;

    short* Qp = (short*)d_ws;
    float* qb = (float*)((char*)d_ws + (size_t)N_ARGS * DM * sizeof(short));

    qproj_kernel<<<256, 256, 0, stream>>>(arg_values, W, b, Qp, qb);
    main_kernel<<<BSZ * 64, 256, 0, stream>>>(ctx_values, Qp, qb, out);
}

// Round 4
// 91.540 us; speedup vs baseline: 1.0848x; 1.0393x over previous
//
#include <hip/hip_runtime.h>
#include <hip/hip_bf16.h>

// ArgumentLocalLogits: BS=16, CTX_PER=1024, ARGS_PER=32, KEY_DIM=128, D_MODEL=512
// rows[p] = p>>10 ; logits[p] = dot(Q[p>>10], keys[(p>>15)*1024 + (p&1023)])
// Restructure: logits = (Q @ W^T) @ ctx^T + Q.b
// ws: Qp bf16 [512][512] + qb f32 [512]
// out: [P floats rows-as-float][P floats logits]
//
// R10 = exact R6/R4 structure (best measured: 91.30/91.67; R7/R8/R9 direct-load
// rewrites all regressed: staging's 1KB-contiguous wave-instructions beat
// scattered per-lane fragment loads) with ONE change: packed f32->bf16 via
// __float22bfloat162_rn (v_cvt_pk_bf16_f32; ~4x fewer VALU ops on the
// pre-barrier stage critical path). Numerics identical (RNE), validated R8/R9.

#define BSZ        16
#define CTX_PER    1024
#define ARGS_PER   32
#define KD         128
#define DM         512
#define N_ARGS     (BSZ * ARGS_PER)    // 512
#define P_TOTAL    (N_ARGS * CTX_PER)  // 524288

typedef __attribute__((ext_vector_type(8))) short short8;
typedef __attribute__((ext_vector_type(4))) float float4v;

__device__ inline short bf16_of(float x) {
    unsigned u = __builtin_bit_cast(unsigned, x);
    unsigned r = (u + 0x7fffu + ((u >> 16) & 1u)) >> 16;   // RNE
    return (short)r;
}

// packed RNE conversion: lowers to v_cvt_pk_bf16_f32 (2 elts/instr)
__device__ inline short8 cvt8(float4 lo, float4 hi) {
    union { short8 s; __hip_bfloat162 h[4]; } u;
    u.h[0] = __float22bfloat162_rn(make_float2(lo.x, lo.y));
    u.h[1] = __float22bfloat162_rn(make_float2(lo.z, lo.w));
    u.h[2] = __float22bfloat162_rn(make_float2(hi.x, hi.y));
    u.h[3] = __float22bfloat162_rn(make_float2(hi.z, hi.w));
    return u.s;
}

// Qp[a][m] = sum_d arg[a][d] * W[m][d]  (bf16), qb[a] = dot(arg[a], b)
// grid 256: mtile = b>>3 (16 args), ntile = (b&7)*4 + wave (16 W-rows). 1 MFMA tile per wave.
__global__ __launch_bounds__(256) void qproj_kernel(
    const float* __restrict__ arg, const float* __restrict__ W,
    const float* __restrict__ b, short* __restrict__ Qp, float* __restrict__ qb)
{
    const int t = threadIdx.x, lane = t & 63, wave = t >> 6;
    const int mtile = blockIdx.x >> 3;
    const int ntile = (blockIdx.x & 7) * 4 + wave;
    const int n = lane & 15, quad = lane >> 4;

    // A[m=arg][k=d]: m = lane&15, k = quad*8+j
    const float* asrc = arg + (size_t)(mtile * 16 + n) * KD + quad * 8;
    short8 afr[4];
    #pragma unroll
    for (int kt = 0; kt < 4; ++kt)
        afr[kt] = cvt8(*(const float4*)(asrc + kt * 32), *(const float4*)(asrc + kt * 32 + 4));

    // B[k=d][n=W-row]: n = lane&15
    const float* wsrc = W + (size_t)(ntile * 16 + n) * KD + quad * 8;
    float4v acc = {0.f, 0.f, 0.f, 0.f};
    #pragma unroll
    for (int kt = 0; kt < 4; ++kt) {
        short8 bfr = cvt8(*(const float4*)(wsrc + kt * 32), *(const float4*)(wsrc + kt * 32 + 4));
        acc = __builtin_amdgcn_mfma_f32_16x16x32_bf16(afr[kt], bfr, acc, 0, 0, 0);
    }
    // D: col = lane&15 (= W row-in-tile), row = quad*4+r (= arg-in-tile)
    #pragma unroll
    for (int r = 0; r < 4; ++r)
        Qp[(size_t)(mtile * 16 + quad * 4 + r) * DM + ntile * 16 + n] = bf16_of(acc[r]);

    // qb: only one n-group per m-tile computes it
    if ((blockIdx.x & 7) == 0) {
        __shared__ float red[16][17];
        const int al = t >> 4, seg = t & 15;
        const float* qrow = arg + (size_t)(mtile * 16 + al) * KD + seg * 8;
        float p = 0.f;
        #pragma unroll
        for (int j = 0; j < 8; ++j) p += qrow[j] * b[seg * 8 + j];
        red[al][seg] = p;
        __syncthreads();
        if (t < 16) {
            float ssum = 0.f;
            #pragma unroll
            for (int j = 0; j < 16; ++j) ssum += red[t][j];
            qb[mtile * 16 + t] = ssum;
        }
    }
}

// grid 1024 = 16 states x 64 chunks of 16 ctx rows. 4 waves split K=512 (128 each).
// ctx is staged through LDS with COALESCED float4 loads (cvt to bf16 at staging);
// B-fragments then come from LDS as short8 (pad +8 shorts -> 2-way alias, free).
__global__ __launch_bounds__(256, 3) void main_kernel(
    const float* __restrict__ ctx, const short* __restrict__ Qp,
    const float* __restrict__ qb, float* __restrict__ out)
{
    __shared__ __align__(16) short Qpl[32][520];   // 33280 B
    __shared__ __align__(16) short Cxl[16][520];   // 16640 B  (total 49920 -> 3 blocks/CU)

    const int t = threadIdx.x, lane = t & 63, wave = t >> 6;
    const int s = blockIdx.x >> 6;
    const int chunk = blockIdx.x & 63;

    // stage Qp_s (32x512 bf16 = 32 KB): 2048 16B-units, coalesced
    const short* qsrc = Qp + (size_t)s * 32 * DM;
    #pragma unroll
    for (int i = 0; i < 8; ++i) {
        const int u = i * 256 + t;
        const int row = u >> 6, c = u & 63;
        *(float4*)&Qpl[row][c * 8] = *(const float4*)(qsrc + (size_t)row * DM + c * 8);
    }
    // stage ctx chunk (16x512 fp32 -> bf16): 1024 8-float units, coalesced float4 pairs
    const float* csrc = ctx + (size_t)(s * CTX_PER + chunk * 16) * DM;
    #pragma unroll
    for (int i = 0; i < 4; ++i) {
        const int u = i * 256 + t;
        const int row = u >> 6, c8 = u & 63;
        const float4 lo = *(const float4*)(csrc + (size_t)row * DM + c8 * 8);
        const float4 hi = *(const float4*)(csrc + (size_t)row * DM + c8 * 8 + 4);
        *(short8*)&Cxl[row][c8 * 8] = cvt8(lo, hi);
    }
    __syncthreads();

    const int n = lane & 15, quad = lane >> 4;
    const int k0 = wave * 128;                      // this wave's K-slice

    float4v acc0 = {0.f, 0.f, 0.f, 0.f};
    float4v acc1 = {0.f, 0.f, 0.f, 0.f};
    #pragma unroll
    for (int kt = 0; kt < 4; ++kt) {
        // B[k][n=ctx row]: bfr[j] = ctx[n][k0+kt*32+quad*8+j]
        short8 bfr = *(const short8*)&Cxl[n][k0 + kt * 32 + quad * 8];
        short8 a0  = *(const short8*)&Qpl[n][k0 + kt * 32 + quad * 8];
        short8 a1  = *(const short8*)&Qpl[16 + n][k0 + kt * 32 + quad * 8];
        acc0 = __builtin_amdgcn_mfma_f32_16x16x32_bf16(a0, bfr, acc0, 0, 0, 0);
        acc1 = __builtin_amdgcn_mfma_f32_16x16x32_bf16(a1, bfr, acc1, 0, 0, 0);
    }

    __syncthreads();                                // all waves done with LDS tiles
    float* Sp = (float*)&Qpl[0][0];                 // overlay: [wave][32 args][16 cols]
    // D: col = lane&15 = ctx row-in-tile, row = quad*4+r = arg-in-tile
    #pragma unroll
    for (int r = 0; r < 4; ++r) {
        Sp[wave * 512 + (quad * 4 + r) * 16 + n]      = acc0[r];
        Sp[wave * 512 + (16 + quad * 4 + r) * 16 + n] = acc1[r];
    }
    __syncthreads();

    // reduce 4 wave-partials + qb, write logits + rows (float2)
    const int a = t >> 3, c2 = (t & 7) * 2;
    const int base = a * 16 + c2;
    float v0 = Sp[base]     + Sp[512 + base]     + Sp[1024 + base]     + Sp[1536 + base];
    float v1 = Sp[base + 1] + Sp[512 + base + 1] + Sp[1024 + base + 1] + Sp[1536 + base + 1];
    const int ga = s * ARGS_PER + a;
    const float qbv = qb[ga];
    const size_t off = (size_t)ga * CTX_PER + chunk * 16 + c2;
    *(float2*)(out + P_TOTAL + off) = make_float2(v0 + qbv, v1 + qbv);
    *(float2*)(out + off)           = make_float2((float)ga, (float)ga);
}

extern "C" void kernel_launch(void* const* d_in, const int* in_sizes, int n_in,
                              void* d_out, int out_size, void* d_ws, size_t ws_size,
                              hipStream_t stream)
{
    // setup_inputs order: bs, arg_ids, ctx_ids, arg_values, ctx_values, W, b
    const float* arg_values = (const float*)d_in[3];
    const float* ctx_values = (const float*)d_in[4];
    const float* W          = (const float*)d_in[5];
    const float* b          = (const float*)d_in[6];
    float* out = (float*)d_out;

    short* Qp = (short*)d_ws;
    float* qb = (float*)((char*)d_ws + (size_t)N_ARGS * DM * sizeof(short));

    qproj_kernel<<<256, 256, 0, stream>>>(arg_values, W, b, Qp, qb);
    main_kernel<<<BSZ * 64, 256, 0, stream>>>(ctx_values, Qp, qb, out);
}